// Round 1
// baseline (15.807 us; speedup 1.0000x reference)
//
#include <hip/hip_runtime.h>

// Analytic collapse of the 4-qubit RY + CNOT-ring circuit:
//   <Z0> = c1*c2*c3, <Z1> = c0*c1, <Z2> = c0*c1*c2, <Z3> = c0*c1*c2*c3
// where ci = cos(theta_i). Derivation: CNOT chain is a basis permutation;
// final[i,j,k,l] = init[i^l, j^i^l, k^j, l^k]; marginal sums factor into
// 1 or cos(theta) per qubit depending on XOR parity of the sign bit.

__global__ void qqf_kernel(const float4* __restrict__ x,
                           float4* __restrict__ out, int B) {
    int idx = blockIdx.x * blockDim.x + threadIdx.x;
    int stride = gridDim.x * blockDim.x;
    for (int b = idx; b < B; b += stride) {
        float4 t = x[b];
        float c0 = __cosf(t.x);
        float c1 = __cosf(t.y);
        float c2 = __cosf(t.z);
        float c3 = __cosf(t.w);
        float4 o;
        o.y = c0 * c1;        // <Z1>
        o.z = o.y * c2;       // <Z2>
        o.w = o.z * c3;       // <Z3>
        o.x = c1 * c2 * c3;   // <Z0>
        out[b] = o;
    }
}

extern "C" void kernel_launch(void* const* d_in, const int* in_sizes, int n_in,
                              void* d_out, int out_size, void* d_ws, size_t ws_size,
                              hipStream_t stream) {
    const float4* x = (const float4*)d_in[0];
    float4* out = (float4*)d_out;
    int B = in_sizes[0] / 4;   // [B,4] float32 -> B float4 rows
    const int block = 256;
    int grid = (B + block - 1) / block;
    if (grid > 2048) grid = 2048;
    qqf_kernel<<<grid, block, 0, stream>>>(x, out, B);
}

// Round 3
// 14.894 us; speedup vs baseline: 1.0613x; 1.0613x over previous
//
#include <hip/hip_runtime.h>

// Analytic collapse of the 4-qubit RY + CNOT-ring circuit:
//   <Z0> = c1*c2*c3, <Z1> = c0*c1, <Z2> = c0*c1*c2, <Z3> = c0*c1*c2*c3
// where ci = cos(theta_i).
//
// Memory-bound: 32 MiB in + 32 MiB out, zero reuse. Schedule: 4 float4 per
// thread (strided, coalesced), all loads issued before compute for MLP/ILP,
// nontemporal (streaming) loads+stores since nothing is re-read.
// Note: nontemporal builtins need a true vector type, not HIP_vector_type.

typedef float f32x4 __attribute__((ext_vector_type(4)));

#define ELEMS_PER_THREAD 4

__global__ __launch_bounds__(256) void qqf_kernel(const f32x4* __restrict__ x,
                                                  f32x4* __restrict__ out, int B) {
    int tid = blockIdx.x * blockDim.x + threadIdx.x;
    int nthreads = gridDim.x * blockDim.x;

    f32x4 t[ELEMS_PER_THREAD];
    int idx[ELEMS_PER_THREAD];
    bool ok[ELEMS_PER_THREAD];

    // Issue all loads back-to-back: 4 independent VMEM ops in flight.
    #pragma unroll
    for (int u = 0; u < ELEMS_PER_THREAD; ++u) {
        idx[u] = tid + u * nthreads;
        ok[u] = idx[u] < B;
        if (ok[u]) t[u] = __builtin_nontemporal_load(&x[idx[u]]);
    }

    #pragma unroll
    for (int u = 0; u < ELEMS_PER_THREAD; ++u) {
        if (!ok[u]) continue;
        float c0 = __cosf(t[u].x);
        float c1 = __cosf(t[u].y);
        float c2 = __cosf(t[u].z);
        float c3 = __cosf(t[u].w);
        f32x4 o;
        o.y = c0 * c1;        // <Z1>
        o.z = o.y * c2;       // <Z2>
        o.w = o.z * c3;       // <Z3>
        o.x = c1 * c2 * c3;   // <Z0>
        __builtin_nontemporal_store(o, &out[idx[u]]);
    }
}

extern "C" void kernel_launch(void* const* d_in, const int* in_sizes, int n_in,
                              void* d_out, int out_size, void* d_ws, size_t ws_size,
                              hipStream_t stream) {
    const f32x4* x = (const f32x4*)d_in[0];
    f32x4* out = (f32x4*)d_out;
    int B = in_sizes[0] / 4;   // [B,4] float32 -> B float4 rows
    const int block = 256;
    int grid = (B + block * ELEMS_PER_THREAD - 1) / (block * ELEMS_PER_THREAD);
    qqf_kernel<<<grid, block, 0, stream>>>(x, out, B);
}